// Round 15
// baseline (1466.316 us; speedup 1.0000x reference)
//
#include <hip/hip_runtime.h>
#include <hip/hip_bf16.h>
#include <cmath>

#define S_LEN 2048
#define DMODEL 4096
#define NH 32
#define HDIM 128
#define HEAVY 256
#define RECENT 256
#define ATTN_SCALE 0.08838834764831845f  // 1/sqrt(128)
#define NEGBIG -3.0e38f
#define MB (1024ull * 1024ull)

typedef __attribute__((ext_vector_type(8))) short short8v;
typedef __attribute__((ext_vector_type(4))) short short4v;
typedef __attribute__((ext_vector_type(4))) float floatx4;

__device__ inline ushort f2bf(float x) {
  __hip_bfloat16 h = __float2bfloat16(x);
  return __builtin_bit_cast(ushort, h);
}
struct Split3 {
  short a, b, c;
};
// Truncation split: x == a+b+c EXACTLY (24 mantissa bits = 3x8). ~6 VALU.
__device__ inline Split3 split3(float x) {
  unsigned u = __float_as_uint(x);
  unsigned u1 = u & 0xFFFF0000u;
  float r1 = x - __uint_as_float(u1);
  unsigned u2 = __float_as_uint(r1) & 0xFFFF0000u;
  float r2 = r1 - __uint_as_float(u2);
  unsigned u3 = __float_as_uint(r2);
  Split3 o;
  o.a = (short)(u1 >> 16);
  o.b = (short)(u2 >> 16);
  o.c = (short)(u3 >> 16);
  return o;
}

__device__ __forceinline__ void gl_lds16(const short* gsrc, short* ldst) {
  __builtin_amdgcn_global_load_lds((const __attribute__((address_space(1))) void*)gsrc,
                                   (__attribute__((address_space(3))) void*)ldst, 16, 0, 0);
}

// ===== elementwise 3-way split: X fp32 -> Xa,Xb,Xc bf16 =====
__global__ void split_mat(const float* __restrict__ X, short* __restrict__ Xa,
                          short* __restrict__ Xb, short* __restrict__ Xc, int n4) {
  int stride = gridDim.x * blockDim.x;
  for (int i = blockIdx.x * blockDim.x + threadIdx.x; i < n4; i += stride) {
    float4 v = reinterpret_cast<const float4*>(X)[i];
    float vv[4] = {v.x, v.y, v.z, v.w};
    short4v a, b, c;
#pragma unroll
    for (int j = 0; j < 4; j++) {
      Split3 t = split3(vv[j]);
      a[j] = t.a; b[j] = t.b; c[j] = t.c;
    }
    reinterpret_cast<short4v*>(Xa)[i] = a;
    reinterpret_cast<short4v*>(Xb)[i] = b;
    reinterpret_cast<short4v*>(Xc)[i] = c;
  }
}

// ===== elementwise fp32 -> bf16 =====
__global__ void to_bf16(const float* __restrict__ X, ushort* __restrict__ Y, int n4) {
  int stride = gridDim.x * blockDim.x;
  for (int i = blockIdx.x * blockDim.x + threadIdx.x; i < n4; i += stride) {
    float4 v = reinterpret_cast<const float4*>(X)[i];
    short4v o;
    o[0] = (short)f2bf(v.x);
    o[1] = (short)f2bf(v.y);
    o[2] = (short)f2bf(v.z);
    o[3] = (short)f2bf(v.w);
    reinterpret_cast<short4v*>(Y)[i] = o;
  }
}

// ===== row norms |q| + per-(head,chunk) max |k|^2 — NO atomics =====
__global__ __launch_bounds__(256) void norms_kernel(const float* __restrict__ Qf,
                                                    const float* __restrict__ Kf,
                                                    float* __restrict__ qn,
                                                    float* __restrict__ mk2p) {
  const int h = blockIdx.x >> 4, ch = blockIdx.x & 15;
  const int wv = threadIdx.x >> 6, lane = threadIdx.x & 63;
  __shared__ float wmax[4];
  float mx = 0.f;
  for (int i = 0; i < 32; i++) {
    int r = ch * 128 + wv * 32 + i;
    const float2 qv =
        *reinterpret_cast<const float2*>(&Qf[(size_t)r * DMODEL + h * HDIM + lane * 2]);
    const float2 kv =
        *reinterpret_cast<const float2*>(&Kf[(size_t)r * DMODEL + h * HDIM + lane * 2]);
    float sq = qv.x * qv.x + qv.y * qv.y;
    float sk = kv.x * kv.x + kv.y * kv.y;
#pragma unroll
    for (int off = 1; off <= 32; off <<= 1) {
      sq += __shfl_xor(sq, off);
      sk += __shfl_xor(sk, off);
    }
    if (lane == 0) qn[h * S_LEN + r] = sqrtf(sq);
    mx = fmaxf(mx, sk);
  }
  if (lane == 0) wmax[wv] = mx;
  __syncthreads();
  if (threadIdx.x == 0)
    mk2p[blockIdx.x] = fmaxf(fmaxf(wmax[0], wmax[1]), fmaxf(wmax[2], wmax[3]));
}

// ===== 6-product GEMM, BOTH operands pre-split, gl_lds staging, pinned B-hoist =====
__global__ __launch_bounds__(256, 3) void gemm6p(
    const short* __restrict__ Aag, const short* __restrict__ Abg, const short* __restrict__ Acg,
    const short* __restrict__ Bag, const short* __restrict__ Bbg, const short* __restrict__ Bcg,
    float* __restrict__ C, int M, int N, int K) {
  __shared__ short LP[6][128 * 32];  // 48KB total
  const int tid = threadIdx.x;
  const int w = tid >> 6, l = tid & 63, g = l >> 4, ln = l & 15;
  const int wm = w >> 1, wn = w & 1;
  const int row0 = blockIdx.y * 128, col0 = blockIdx.x * 128;
  const int wb = tid & 192;
  floatx4 acc[4][4] = {};
  for (int k0 = 0; k0 < K; k0 += 32) {
    __syncthreads();
#pragma unroll
    for (int it = 0; it < 2; it++) {
      int id = it * 256 + tid;
      int r = id >> 2, j = id & 3;
      int cg = j ^ ((r >> 1) & 3);
      size_t ga = (size_t)(row0 + r) * K + k0 + cg * 8;
      size_t gb = (size_t)(col0 + r) * K + k0 + cg * 8;
      int cb = (it * 256 + wb) * 8;
      gl_lds16(Aag + ga, &LP[0][cb]);
      gl_lds16(Abg + ga, &LP[1][cb]);
      gl_lds16(Acg + ga, &LP[2][cb]);
      gl_lds16(Bag + gb, &LP[3][cb]);
      gl_lds16(Bbg + gb, &LP[4][cb]);
      gl_lds16(Bcg + gb, &LP[5][cb]);
    }
    __syncthreads();
    // hoist all 12 B fragments; asm keep-alive pins them in VGPRs (rule #17)
    short8v b1[4], b2[4], b3[4];
#pragma unroll
    for (int j = 0; j < 4; j++) {
      int brow = wn * 64 + j * 16 + ln;
      int boff = brow * 32 + ((g ^ ((brow >> 1) & 3)) * 8);
      b1[j] = *reinterpret_cast<const short8v*>(&LP[3][boff]);
      b2[j] = *reinterpret_cast<const short8v*>(&LP[4][boff]);
      b3[j] = *reinterpret_cast<const short8v*>(&LP[5][boff]);
    }
#pragma unroll
    for (int i = 0; i < 4; i++) {
      asm volatile("" ::"v"(b1[0]), "v"(b1[1]), "v"(b1[2]), "v"(b1[3]), "v"(b2[0]), "v"(b2[1]),
                   "v"(b2[2]), "v"(b2[3]), "v"(b3[0]), "v"(b3[1]), "v"(b3[2]), "v"(b3[3]));
      int arow = wm * 64 + i * 16 + ln;
      int aoff = arow * 32 + ((g ^ ((arow >> 1) & 3)) * 8);
      short8v a1 = *reinterpret_cast<const short8v*>(&LP[0][aoff]);
      short8v a2 = *reinterpret_cast<const short8v*>(&LP[1][aoff]);
      short8v a3 = *reinterpret_cast<const short8v*>(&LP[2][aoff]);
#pragma unroll
      for (int j = 0; j < 4; j++) {
        acc[i][j] = __builtin_amdgcn_mfma_f32_16x16x32_bf16(a1, b1[j], acc[i][j], 0, 0, 0);
        acc[i][j] = __builtin_amdgcn_mfma_f32_16x16x32_bf16(a1, b2[j], acc[i][j], 0, 0, 0);
        acc[i][j] = __builtin_amdgcn_mfma_f32_16x16x32_bf16(a2, b1[j], acc[i][j], 0, 0, 0);
        acc[i][j] = __builtin_amdgcn_mfma_f32_16x16x32_bf16(a1, b3[j], acc[i][j], 0, 0, 0);
        acc[i][j] = __builtin_amdgcn_mfma_f32_16x16x32_bf16(a2, b2[j], acc[i][j], 0, 0, 0);
        acc[i][j] = __builtin_amdgcn_mfma_f32_16x16x32_bf16(a3, b1[j], acc[i][j], 0, 0, 0);
      }
    }
  }
#pragma unroll
  for (int i = 0; i < 4; i++)
#pragma unroll
    for (int j = 0; j < 4; j++)
#pragma unroll
      for (int r = 0; r < 4; r++)
        C[(size_t)(row0 + wm * 64 + i * 16 + g * 4 + r) * N + col0 + wn * 64 + j * 16 + ln] =
            acc[i][j][r];
}

// ===== 6-product GEMM, A pre-split, B split in-kernel (fallback) =====
__global__ __launch_bounds__(256) void gemm6h(const short* __restrict__ Aag,
                                              const short* __restrict__ Abg,
                                              const short* __restrict__ Acg,
                                              const float* __restrict__ B,
                                              float* __restrict__ C, int M, int N, int K) {
  __shared__ short Aa[128 * 40], Ab[128 * 40], Ac[128 * 40];
  __shared__ short Ba[128 * 40], Bb[128 * 40], Bc[128 * 40];
  const int tid = threadIdx.x;
  const int w = tid >> 6, l = tid & 63, g = l >> 4, ln = l & 15;
  const int wm = w >> 1, wn = w & 1;
  const int row0 = blockIdx.y * 128, col0 = blockIdx.x * 128;
  floatx4 acc[4][4] = {};
  for (int k0 = 0; k0 < K; k0 += 32) {
    __syncthreads();
#pragma unroll
    for (int i = 0; i < 2; i++) {
      int id = tid + i * 256;
      int r = id >> 2, c = id & 3;
      size_t ga = (size_t)(row0 + r) * K + k0 + c * 8;
      int o = r * 40 + c * 8;
      *reinterpret_cast<short8v*>(&Aa[o]) = *reinterpret_cast<const short8v*>(&Aag[ga]);
      *reinterpret_cast<short8v*>(&Ab[o]) = *reinterpret_cast<const short8v*>(&Abg[ga]);
      *reinterpret_cast<short8v*>(&Ac[o]) = *reinterpret_cast<const short8v*>(&Acg[ga]);
    }
#pragma unroll
    for (int i = 0; i < 4; i++) {
      int id = tid + i * 256;
      int r = id >> 3, c4 = id & 7;
      float4 bv = *reinterpret_cast<const float4*>(&B[(size_t)(col0 + r) * K + k0 + c4 * 4]);
      float bf[4] = {bv.x, bv.y, bv.z, bv.w};
      short4v b1, b2, b3;
#pragma unroll
      for (int j = 0; j < 4; j++) {
        Split3 t = split3(bf[j]);
        b1[j] = t.a; b2[j] = t.b; b3[j] = t.c;
      }
      int o = r * 40 + c4 * 4;
      *reinterpret_cast<short4v*>(&Ba[o]) = b1;
      *reinterpret_cast<short4v*>(&Bb[o]) = b2;
      *reinterpret_cast<short4v*>(&Bc[o]) = b3;
    }
    __syncthreads();
#pragma unroll
    for (int i = 0; i < 4; i++) {
      int ar = (wm * 64 + i * 16 + ln) * 40 + g * 8;
      short8v a1 = *reinterpret_cast<const short8v*>(&Aa[ar]);
      short8v a2 = *reinterpret_cast<const short8v*>(&Ab[ar]);
      short8v a3 = *reinterpret_cast<const short8v*>(&Ac[ar]);
#pragma unroll
      for (int j = 0; j < 4; j++) {
        int br = (wn * 64 + j * 16 + ln) * 40 + g * 8;
        short8v b1 = *reinterpret_cast<const short8v*>(&Ba[br]);
        short8v b2 = *reinterpret_cast<const short8v*>(&Bb[br]);
        short8v b3 = *reinterpret_cast<const short8v*>(&Bc[br]);
        acc[i][j] = __builtin_amdgcn_mfma_f32_16x16x32_bf16(a1, b1, acc[i][j], 0, 0, 0);
        acc[i][j] = __builtin_amdgcn_mfma_f32_16x16x32_bf16(a1, b2, acc[i][j], 0, 0, 0);
        acc[i][j] = __builtin_amdgcn_mfma_f32_16x16x32_bf16(a2, b1, acc[i][j], 0, 0, 0);
        acc[i][j] = __builtin_amdgcn_mfma_f32_16x16x32_bf16(a1, b3, acc[i][j], 0, 0, 0);
        acc[i][j] = __builtin_amdgcn_mfma_f32_16x16x32_bf16(a2, b2, acc[i][j], 0, 0, 0);
        acc[i][j] = __builtin_amdgcn_mfma_f32_16x16x32_bf16(a3, b1, acc[i][j], 0, 0, 0);
      }
    }
  }
#pragma unroll
  for (int i = 0; i < 4; i++)
#pragma unroll
    for (int j = 0; j < 4; j++)
#pragma unroll
      for (int r = 0; r < 4; r++)
        C[(size_t)(row0 + wm * 64 + i * 16 + g * 4 + r) * N + col0 + wn * 64 + j * 16 + ln] =
            acc[i][j][r];
}

// ===== pure-bf16 GEMM: C = A[M][K] * B[N][K]^T, gl_lds dbuf staging =====
template <int TOUT>
__global__ __launch_bounds__(256, 3) void gemm_bb(const short* __restrict__ A,
                                                  const short* __restrict__ B, void* Cv, int M,
                                                  int N, int K) {
  __shared__ short KS[2][2][128 * 32];  // 32KB dbuf
  const int tid = threadIdx.x;
  const int w = tid >> 6, l = tid & 63, g = l >> 4, ln = l & 15;
  const int wm = w >> 1, wn = w & 1;
  const int row0 = blockIdx.y * 128, col0 = blockIdx.x * 128;
  const int wb = tid & 192;
  floatx4 acc[4][4] = {};
  const int nt = K / 32;
  auto issue = [&](int k0, int buf) {
#pragma unroll
    for (int it = 0; it < 2; it++) {
      int id = it * 256 + tid;
      int r = id >> 2, j = id & 3;
      int cg = j ^ ((r >> 1) & 3);
      size_t ga = (size_t)(row0 + r) * K + k0 + cg * 8;
      size_t gb = (size_t)(col0 + r) * K + k0 + cg * 8;
      int cb = (it * 256 + wb) * 8;
      gl_lds16(A + ga, &KS[buf][0][cb]);
      gl_lds16(B + gb, &KS[buf][1][cb]);
    }
  };
  issue(0, 0);
  __syncthreads();
  for (int t = 0; t < nt; t++) {
    const int cur = t & 1;
    if (t + 1 < nt) issue((t + 1) * 32, cur ^ 1);
    short8v b[4];
#pragma unroll
    for (int j = 0; j < 4; j++) {
      int brow = wn * 64 + j * 16 + ln;
      b[j] = *reinterpret_cast<const short8v*>(
          &KS[cur][1][brow * 32 + ((g ^ ((brow >> 1) & 3)) * 8)]);
    }
#pragma unroll
    for (int i = 0; i < 4; i++) {
      asm volatile("" ::"v"(b[0]), "v"(b[1]), "v"(b[2]), "v"(b[3]));
      int arow = wm * 64 + i * 16 + ln;
      short8v a = *reinterpret_cast<const short8v*>(
          &KS[cur][0][arow * 32 + ((g ^ ((arow >> 1) & 3)) * 8)]);
#pragma unroll
      for (int j = 0; j < 4; j++)
        acc[i][j] = __builtin_amdgcn_mfma_f32_16x16x32_bf16(a, b[j], acc[i][j], 0, 0, 0);
    }
    __syncthreads();
  }
  if (TOUT == 0) {
    float* C = (float*)Cv;
#pragma unroll
    for (int i = 0; i < 4; i++)
#pragma unroll
      for (int j = 0; j < 4; j++)
#pragma unroll
        for (int r = 0; r < 4; r++)
          C[(size_t)(row0 + wm * 64 + i * 16 + g * 4 + r) * N + col0 + wn * 64 + j * 16 + ln] =
              acc[i][j][r];
  } else {
    ushort* Vt = (ushort*)Cv;
#pragma unroll
    for (int i = 0; i < 4; i++)
#pragma unroll
      for (int j = 0; j < 4; j++) {
        short4v o;
#pragma unroll
        for (int r = 0; r < 4; r++) o[r] = (short)f2bf(acc[i][j][r]);
        size_t n = col0 + wn * 64 + j * 16 + ln;
        size_t m0 = row0 + wm * 64 + i * 16 + g * 4;
        *reinterpret_cast<short4v*>(&Vt[n * M + m0]) = o;
      }
  }
}

// ===== RoPE + 3-way split of Q,K =====
__global__ void rope_convert(const float* __restrict__ Q, const float* __restrict__ K,
                             const int* __restrict__ pos, short* __restrict__ Qa,
                             short* __restrict__ Qb, short* __restrict__ Qc,
                             short* __restrict__ Ka, short* __restrict__ Kb,
                             short* __restrict__ Kc) {
  int idx = blockIdx.x * blockDim.x + threadIdx.x;
  if (idx >= S_LEN * 64) return;
  int d = idx & 63;
  int r = idx >> 6;
  float p = (float)pos[r];
  float invf = (float)pow(10000.0, -(double)(2 * d) / 128.0);
  float ang = p * invf;
  float c = cosf(ang), s = sinf(ang);
  for (int h = 0; h < NH; h++) {
    size_t base = (size_t)r * DMODEL + h * HDIM + d;
    float q1 = Q[base], q2 = Q[base + 64];
    float k1 = K[base], k2 = K[base + 64];
    float qa = q1 * c - q2 * s, qb = q2 * c + q1 * s;
    float ka = k1 * c - k2 * s, kb = k2 * c + k1 * s;
    Split3 t;
    t = split3(qa); Qa[base] = t.a; Qb[base] = t.b; Qc[base] = t.c;
    t = split3(qb); Qa[base + 64] = t.a; Qb[base + 64] = t.b; Qc[base + 64] = t.c;
    t = split3(ka); Ka[base] = t.a; Kb[base] = t.b; Kc[base] = t.c;
    t = split3(kb); Ka[base + 64] = t.a; Kb[base + 64] = t.b; Kc[base + 64] = t.c;
  }
}

// ===== fused flash attention: QB=64, 4 waves, bound-softmax, dbuf gl_lds =====
#define KVB 32
#define KSPL (KVB * 128)

__device__ __forceinline__ floatx4 qk6_tile(const short* KaS, const short* KbS,
                                            const short* KcS, const short8v q1[4],
                                            const short8v q2[4], const short8v q3[4],
                                            int krow, int g) {
  floatx4 cA = {}, cB = {}, cC = {}, cD = {}, cE = {}, cF = {};
#pragma unroll
  for (int dc = 0; dc < 4; dc++) {
    int didx = krow * 128 + ((dc * 32 + g * 8) ^ ((krow & 7) << 3));
    short8v k1 = *reinterpret_cast<const short8v*>(&KaS[didx]);
    short8v k2 = *reinterpret_cast<const short8v*>(&KbS[didx]);
    short8v k3 = *reinterpret_cast<const short8v*>(&KcS[didx]);
    cA = __builtin_amdgcn_mfma_f32_16x16x32_bf16(q1[dc], k1, cA, 0, 0, 0);
    cB = __builtin_amdgcn_mfma_f32_16x16x32_bf16(q1[dc], k2, cB, 0, 0, 0);
    cC = __builtin_amdgcn_mfma_f32_16x16x32_bf16(q2[dc], k1, cC, 0, 0, 0);
    cD = __builtin_amdgcn_mfma_f32_16x16x32_bf16(q1[dc], k3, cD, 0, 0, 0);
    cE = __builtin_amdgcn_mfma_f32_16x16x32_bf16(q2[dc], k2, cE, 0, 0, 0);
    cF = __builtin_amdgcn_mfma_f32_16x16x32_bf16(q3[dc], k1, cF, 0, 0, 0);
  }
  return ((cA + cB) + (cC + cD)) + (cE + cF);
}

__device__ __forceinline__ void issue_tile(const short* __restrict__ Ka,
                                           const short* __restrict__ Kb,
                                           const short* __restrict__ Kc, int k0, int h,
                                           short* bufA, short* bufB, short* bufC, int tid) {
  const int wb = tid & 192;
#pragma unroll
  for (int it = 0; it < 2; it++) {
    int j = it * 256 + tid;
    int r = j >> 4, cl = j & 15;
    int cg = cl ^ (r & 7);
    size_t goff = (size_t)(k0 + r) * DMODEL + h * HDIM + cg * 8;
    int cb = (it * 256 + wb) * 8;
    gl_lds16(Ka + goff, bufA + cb);
    gl_lds16(Kb + goff, bufB + cb);
    gl_lds16(Kc + goff, bufC + cb);
  }
}

__global__ __launch_bounds__(256, 3) void attn_fused(
    const short* __restrict__ Qa, const short* __restrict__ Qb, const short* __restrict__ Qc,
    const short* __restrict__ Ka, const short* __restrict__ Kb, const short* __restrict__ Kc,
    const ushort* __restrict__ Vt, const float* __restrict__ qn,
    const float* __restrict__ mk2p, ushort* __restrict__ AObf, float* __restrict__ sp4) {
  __shared__ short KS[2][3][KSPL];  // 48KB
  __shared__ short Ps[4 * 512];     // 4KB
  const int bid = blockIdx.x;
  const int qb = 31 - (bid >> 5);  // LPT
  const int h = bid & 31;
  const int tid = threadIdx.x;
  const int w = tid >> 6, g = (tid >> 4) & 3, ln = tid & 15;
  const int q0 = qb * 64;
  const int qrow = q0 + w * 16 + ln;
  short8v q1[4], q2[4], q3[4];
#pragma unroll
  for (int dc = 0; dc < 4; dc++) {
    size_t off = (size_t)qrow * DMODEL + h * HDIM + dc * 32 + g * 8;
    q1[dc] = *reinterpret_cast<const short8v*>(&Qa[off]);
    q2[dc] = *reinterpret_cast<const short8v*>(&Qb[off]);
    q3[dc] = *reinterpret_cast<const short8v*>(&Qc[off]);
  }
  float mkv = 0.f;
#pragma unroll
  for (int j = 0; j < 16; j++) mkv = fmaxf(mkv, mk2p[h * 16 + j]);
  const float mk = sqrtf(mkv);
  float B_r[4], l_r[4];
#pragma unroll
  for (int r = 0; r < 4; r++) {
    B_r[r] = qn[h * S_LEN + q0 + w * 16 + g * 4 + r] * mk * ATTN_SCALE;
    l_r[r] = 0.f;
  }
  const int nkt = 2 * qb + 2;

  // ---- pass 1 ----
  issue_tile(Ka, Kb, Kc, 0, h, KS[0][0], KS[0][1], KS[0][2], tid);
  __syncthreads();
  for (int t = 0; t < nkt; t++) {
    const int k0 = t * KVB;
    const int cur = t & 1;
    if (t + 1 < nkt)
      issue_tile(Ka, Kb, Kc, k0 + KVB, h, KS[cur ^ 1][0], KS[cur ^ 1][1], KS[cur ^ 1][2], tid);
#pragma unroll
    for (int ct = 0; ct < 2; ct++) {
      floatx4 sacc = qk6_tile(KS[cur][0], KS[cur][1], KS[cur][2], q1, q2, q3, ct * 16 + ln, g);
#pragma unroll
      for (int r = 0; r < 4; r++) {
        float s = sacc[r] * ATTN_SCALE;
        int key = k0 + ct * 16 + ln;
        int qq = q0 + w * 16 + g * 4 + r;
        l_r[r] += (key <= qq) ? __expf(s - B_r[r]) : 0.f;
      }
    }
    __syncthreads();
  }
  float inv_l[4];
#pragma unroll
  for (int r = 0; r < 4; r++) {
    float l = l_r[r];
    l += __shfl_xor(l, 1);
    l += __shfl_xor(l, 2);
    l += __shfl_xor(l, 4);
    l += __shfl_xor(l, 8);
    inv_l[r] = 1.0f / l;
  }

  // ---- pass 2 ----
  floatx4 o[8] = {};
  issue_tile(Ka, Kb, Kc, 0, h, KS[0][0], KS[0][1], KS[0][2], tid);
  __syncthreads();
  for (int t = 0; t < nkt; t++) {
    const int k0 = t * KVB;
    const int cur = t & 1;
    if (t + 1 < nkt)
      issue_tile(Ka, Kb, Kc, k0 + KVB, h, KS[cur ^ 1][0], KS[cur ^ 1][1], KS[cur ^ 1][2], tid);
    float pv[2][4];
#pragma unroll
    for (int ct = 0; ct < 2; ct++) {
      floatx4 sacc = qk6_tile(KS[cur][0], KS[cur][1], KS[cur][2], q1, q2, q3, ct * 16 + ln, g);
#pragma unroll
      for (int r = 0; r < 4; r++) {
        float s = sacc[r] * ATTN_SCALE;
        int key = k0 + ct * 16 + ln;
        int qq = q0 + w * 16 + g * 4 + r;
        float e = (key <= qq) ? __expf(s - B_r[r]) : 0.f;
        pv[ct][r] = e * inv_l[r];
      }
    }
#pragma unroll
    for (int ct = 0; ct < 2; ct++) {
      float c2 = pv[ct][0] + pv[ct][1] + pv[ct][2] + pv[ct][3];
      c2 += __shfl_xor(c2, 16);
      c2 += __shfl_xor(c2, 32);
      if (g == 0) sp4[((size_t)(qb * 4 + w) * NH + h) * S_LEN + k0 + ct * 16 + ln] = c2;
    }
#pragma unroll
    for (int ct = 0; ct < 2; ct++)
#pragma unroll
      for (int r = 0; r < 4; r++) {
        int prow = g * 4 + r, pcol = ct * 16 + ln;
        int col = ((((pcol >> 3) ^ (prow >> 2)) & 3) << 3) | (pcol & 7);
        Ps[w * 512 + prow * 32 + col] = (short)f2bf(pv[ct][r]);
      }
    short8v pa = *reinterpret_cast<const short8v*>(
        &Ps[w * 512 + ln * 32 + (((g ^ (ln >> 2)) & 3) << 3)]);
#pragma unroll
    for (int ctd = 0; ctd < 8; ctd++) {
      size_t voff = ((size_t)h * HDIM + ctd * 16 + ln) * S_LEN + k0 + g * 8;
      short8v vb = *reinterpret_cast<const short8v*>(&Vt[voff]);
      o[ctd] = __builtin_amdgcn_mfma_f32_16x16x32_bf16(pa, vb, o[ctd], 0, 0, 0);
    }
    __syncthreads();
  }
#pragma unroll
  for (int ctd = 0; ctd < 8; ctd++)
#pragma unroll
    for (int r = 0; r < 4; r++)
      AObf[(size_t)(q0 + w * 16 + g * 4 + r) * DMODEL + h * HDIM + ctd * 16 + ln] =
          f2bf(o[ctd][r]);
}

// ---------------- reduce column-sum partials (128 per (h,k)) ----------------
__global__ void reduce_scores(const float* __restrict__ sp4, float* __restrict__ scores) {
  int idx = blockIdx.x * blockDim.x + threadIdx.x;
  if (idx >= NH * S_LEN) return;
  int h = idx >> 11, k = idx & 2047;
  float s = 0.f;
  for (int j = 0; j < 128; j++) s += sp4[((size_t)j * NH + h) * S_LEN + k];
  scores[idx] = s;
}

// ---------------- per-head exact top-256 + mask + previous_scores ----------------
__global__ __launch_bounds__(256) void topk_mask_kernel(const float* __restrict__ scores,
                                                        float* __restrict__ out_mask,
                                                        float* __restrict__ prev_scores) {
  const int h = blockIdx.x;
  __shared__ unsigned sb[S_LEN - RECENT];
  __shared__ int cnt_sh;
  const int NSEL = S_LEN - RECENT;
  const int tid = threadIdx.x;
  const float* sc = scores + (size_t)h * S_LEN;
  for (int i = tid; i < NSEL; i += 256) sb[i] = __float_as_uint(sc[i]);
  __syncthreads();
  unsigned prefix = 0u;
  for (int b = 31; b >= 0; b--) {
    unsigned cand = prefix | (1u << b);
    if (tid == 0) cnt_sh = 0;
    __syncthreads();
    int c = 0;
    for (int i = tid; i < NSEL; i += 256) c += (sb[i] >= cand) ? 1 : 0;
    atomicAdd(&cnt_sh, c);
    __syncthreads();
    if (cnt_sh >= HEAVY) prefix = cand;
    __syncthreads();
  }
  if (tid == 0) cnt_sh = 0;
  __syncthreads();
  int c = 0;
  for (int i = tid; i < NSEL; i += 256) c += (sb[i] > prefix) ? 1 : 0;
  atomicAdd(&cnt_sh, c);
  __syncthreads();
  const int c1 = cnt_sh;
  float* mrow = out_mask + (size_t)h * (S_LEN + 1);
  float* prow = prev_scores + (size_t)h * S_LEN;
  for (int j = NSEL + tid; j < S_LEN + 1; j += 256) mrow[j] = 1.0f;
  for (int k = NSEL + tid; k < S_LEN; k += 256) prow[k] = sc[k];
  for (int i = tid; i < NSEL; i += 256) {
    bool sel = sb[i] > prefix;
    mrow[i] = sel ? 1.f : 0.f;
    prow[i] = sel ? sc[i] : 0.f;
  }
  __syncthreads();
  if (tid == 0) {
    int need = HEAVY - c1;
    for (int i = 0; i < NSEL && need > 0; i++) {
      if (sb[i] == prefix) { mrow[i] = 1.f; prow[i] = sc[i]; need--; }
    }
  }
}

extern "C" void kernel_launch(void* const* d_in, const int* in_sizes, int n_in,
                              void* d_out, int out_size, void* d_ws, size_t ws_size,
                              hipStream_t stream) {
  const float* hidden = (const float*)d_in[0];
  const int* pos = (const int*)d_in[2];
  const float* Wq = (const float*)d_in[3];
  const float* Wk = (const float*)d_in[4];
  const float* Wv = (const float*)d_in[5];
  const float* Wo = (const float*)d_in[6];

  float* out0 = (float*)d_out;
  float* out_mask = out0 + (size_t)S_LEN * DMODEL;
  float* prev_scores = out_mask + (size_t)NH * (S_LEN + 1);

  char* ws = (char*)d_ws;
  float* Qf = (float*)(ws + 0 * MB);
  float* Kf = (float*)(ws + 32 * MB);
  ushort* Vt = (ushort*)(ws + 64 * MB);
  short* Ha = (short*)(ws + 80 * MB);
  short* Hb = (short*)(ws + 96 * MB);
  short* Hc = (short*)(ws + 112 * MB);
  short* Qa = (short*)(ws + 80 * MB);
  short* Qb = (short*)(ws + 96 * MB);
  short* Qc = (short*)(ws + 112 * MB);
  short* Ka = (short*)(ws + 128 * MB);
  short* Kb = (short*)(ws + 144 * MB);
  short* Kc = (short*)(ws + 160 * MB);
  ushort* AObf = (ushort*)(ws + 0 * MB);
  float* sp4 = Kf;
  float* scores = (float*)(ws + 64 * MB);
  ushort* Wobf = (ushort*)(ws + 96 * MB);

  float* qn = out0;
  float* mk2p = out0 + NH * S_LEN;

  dim3 gg(DMODEL / 128, S_LEN / 128);
  split_mat<<<2048, 256, 0, stream>>>(hidden, Ha, Hb, Hc, S_LEN * DMODEL / 4);

  ushort* Wvbf;
  if (ws_size >= 224 * MB) {
    short* Wsa = (short*)(ws + 128 * MB);
    short* Wsb = (short*)(ws + 160 * MB);
    short* Wsc = (short*)(ws + 192 * MB);
    split_mat<<<2048, 256, 0, stream>>>(Wq, Wsa, Wsb, Wsc, DMODEL * DMODEL / 4);
    gemm6p<<<gg, 256, 0, stream>>>(Ha, Hb, Hc, Wsa, Wsb, Wsc, Qf, S_LEN, DMODEL, DMODEL);
    split_mat<<<2048, 256, 0, stream>>>(Wk, Wsa, Wsb, Wsc, DMODEL * DMODEL / 4);
    gemm6p<<<gg, 256, 0, stream>>>(Ha, Hb, Hc, Wsa, Wsb, Wsc, Kf, S_LEN, DMODEL, DMODEL);
    Wvbf = (ushort*)(ws + 192 * MB);
  } else {
    gemm6h<<<gg, 256, 0, stream>>>(Ha, Hb, Hc, Wq, Qf, S_LEN, DMODEL, DMODEL);
    gemm6h<<<gg, 256, 0, stream>>>(Ha, Hb, Hc, Wk, Kf, S_LEN, DMODEL, DMODEL);
    Wvbf = (ushort*)(ws + 128 * MB);
  }
  to_bf16<<<2048, 256, 0, stream>>>(Wv, Wvbf, DMODEL * DMODEL / 4);
  gemm_bb<1><<<gg, 256, 0, stream>>>(Ha, (const short*)Wvbf, Vt, S_LEN, DMODEL, DMODEL);

  norms_kernel<<<512, 256, 0, stream>>>(Qf, Kf, qn, mk2p);

  int rope_total = S_LEN * 64;
  rope_convert<<<(rope_total + 255) / 256, 256, 0, stream>>>(Qf, Kf, pos, Qa, Qb, Qc, Ka, Kb, Kc);

  hipError_t _e = hipMemsetAsync(sp4, 0, (size_t)128 * NH * S_LEN * sizeof(float), stream);
  (void)_e;
  attn_fused<<<1024, 256, 0, stream>>>(Qa, Qb, Qc, Ka, Kb, Kc, Vt, qn, mk2p, AObf, sp4);

  to_bf16<<<2048, 256, 0, stream>>>(Wo, Wobf, DMODEL * DMODEL / 4);
  reduce_scores<<<(NH * S_LEN + 255) / 256, 256, 0, stream>>>(sp4, scores);
  topk_mask_kernel<<<NH, 256, 0, stream>>>(scores, out_mask, prev_scores);

  gemm_bb<0><<<gg, 256, 0, stream>>>((const short*)AObf, (const short*)Wobf, out0, S_LEN, DMODEL,
                                     DMODEL);
}

// Round 16
// 1457.172 us; speedup vs baseline: 1.0063x; 1.0063x over previous
//
#include <hip/hip_runtime.h>
#include <hip/hip_bf16.h>
#include <cmath>

#define S_LEN 2048
#define DMODEL 4096
#define NH 32
#define HDIM 128
#define HEAVY 256
#define RECENT 256
#define ATTN_SCALE 0.08838834764831845f  // 1/sqrt(128)
#define NEGBIG -3.0e38f
#define MB (1024ull * 1024ull)

typedef __attribute__((ext_vector_type(8))) short short8v;
typedef __attribute__((ext_vector_type(4))) short short4v;
typedef __attribute__((ext_vector_type(4))) float floatx4;

__device__ inline ushort f2bf(float x) {
  __hip_bfloat16 h = __float2bfloat16(x);
  return __builtin_bit_cast(ushort, h);
}
struct Split3 {
  short a, b, c;
};
// Truncation split: x == a+b+c EXACTLY (24 mantissa bits = 3x8). ~6 VALU.
__device__ inline Split3 split3(float x) {
  unsigned u = __float_as_uint(x);
  unsigned u1 = u & 0xFFFF0000u;
  float r1 = x - __uint_as_float(u1);
  unsigned u2 = __float_as_uint(r1) & 0xFFFF0000u;
  float r2 = r1 - __uint_as_float(u2);
  unsigned u3 = __float_as_uint(r2);
  Split3 o;
  o.a = (short)(u1 >> 16);
  o.b = (short)(u2 >> 16);
  o.c = (short)(u3 >> 16);
  return o;
}

__device__ __forceinline__ void gl_lds16(const short* gsrc, short* ldst) {
  __builtin_amdgcn_global_load_lds((const __attribute__((address_space(1))) void*)gsrc,
                                   (__attribute__((address_space(3))) void*)ldst, 16, 0, 0);
}

// ===== elementwise 3-way split: X fp32 -> Xa,Xb,Xc bf16 =====
__global__ void split_mat(const float* __restrict__ X, short* __restrict__ Xa,
                          short* __restrict__ Xb, short* __restrict__ Xc, int n4) {
  int stride = gridDim.x * blockDim.x;
  for (int i = blockIdx.x * blockDim.x + threadIdx.x; i < n4; i += stride) {
    float4 v = reinterpret_cast<const float4*>(X)[i];
    float vv[4] = {v.x, v.y, v.z, v.w};
    short4v a, b, c;
#pragma unroll
    for (int j = 0; j < 4; j++) {
      Split3 t = split3(vv[j]);
      a[j] = t.a; b[j] = t.b; c[j] = t.c;
    }
    reinterpret_cast<short4v*>(Xa)[i] = a;
    reinterpret_cast<short4v*>(Xb)[i] = b;
    reinterpret_cast<short4v*>(Xc)[i] = c;
  }
}

// ===== elementwise fp32 -> bf16 =====
__global__ void to_bf16(const float* __restrict__ X, ushort* __restrict__ Y, int n4) {
  int stride = gridDim.x * blockDim.x;
  for (int i = blockIdx.x * blockDim.x + threadIdx.x; i < n4; i += stride) {
    float4 v = reinterpret_cast<const float4*>(X)[i];
    short4v o;
    o[0] = (short)f2bf(v.x);
    o[1] = (short)f2bf(v.y);
    o[2] = (short)f2bf(v.z);
    o[3] = (short)f2bf(v.w);
    reinterpret_cast<short4v*>(Y)[i] = o;
  }
}

// ===== row norms |q| + per-(head,chunk) max |k|^2 — NO atomics =====
__global__ __launch_bounds__(256) void norms_kernel(const float* __restrict__ Qf,
                                                    const float* __restrict__ Kf,
                                                    float* __restrict__ qn,
                                                    float* __restrict__ mk2p) {
  const int h = blockIdx.x >> 4, ch = blockIdx.x & 15;
  const int wv = threadIdx.x >> 6, lane = threadIdx.x & 63;
  __shared__ float wmax[4];
  float mx = 0.f;
  for (int i = 0; i < 32; i++) {
    int r = ch * 128 + wv * 32 + i;
    const float2 qv =
        *reinterpret_cast<const float2*>(&Qf[(size_t)r * DMODEL + h * HDIM + lane * 2]);
    const float2 kv =
        *reinterpret_cast<const float2*>(&Kf[(size_t)r * DMODEL + h * HDIM + lane * 2]);
    float sq = qv.x * qv.x + qv.y * qv.y;
    float sk = kv.x * kv.x + kv.y * kv.y;
#pragma unroll
    for (int off = 1; off <= 32; off <<= 1) {
      sq += __shfl_xor(sq, off);
      sk += __shfl_xor(sk, off);
    }
    if (lane == 0) qn[h * S_LEN + r] = sqrtf(sq);
    mx = fmaxf(mx, sk);
  }
  if (lane == 0) wmax[wv] = mx;
  __syncthreads();
  if (threadIdx.x == 0)
    mk2p[blockIdx.x] = fmaxf(fmaxf(wmax[0], wmax[1]), fmaxf(wmax[2], wmax[3]));
}

// ===== 6-product GEMM, BOTH operands pre-split, gl_lds staging =====
// launch_bounds(256,2): lifts unified reg cap to ~256 so the 12 hoisted
// B fragments (48 VGPR) fit alongside 64 AGPR acc — (256,3)'s ~170 cap
// forced the compiler to rematerialize LDS reads (rounds 13/15 post-mortem).
__global__ __launch_bounds__(256, 2) void gemm6p(
    const short* __restrict__ Aag, const short* __restrict__ Abg, const short* __restrict__ Acg,
    const short* __restrict__ Bag, const short* __restrict__ Bbg, const short* __restrict__ Bcg,
    float* __restrict__ C, int M, int N, int K) {
  __shared__ short LP[6][128 * 32];  // 48KB total
  const int tid = threadIdx.x;
  const int w = tid >> 6, l = tid & 63, g = l >> 4, ln = l & 15;
  const int wm = w >> 1, wn = w & 1;
  const int row0 = blockIdx.y * 128, col0 = blockIdx.x * 128;
  const int wb = tid & 192;
  floatx4 acc[4][4] = {};
  for (int k0 = 0; k0 < K; k0 += 32) {
    __syncthreads();
#pragma unroll
    for (int it = 0; it < 2; it++) {
      int id = it * 256 + tid;
      int r = id >> 2, j = id & 3;
      int cg = j ^ ((r >> 1) & 3);
      size_t ga = (size_t)(row0 + r) * K + k0 + cg * 8;
      size_t gb = (size_t)(col0 + r) * K + k0 + cg * 8;
      int cb = (it * 256 + wb) * 8;
      gl_lds16(Aag + ga, &LP[0][cb]);
      gl_lds16(Abg + ga, &LP[1][cb]);
      gl_lds16(Acg + ga, &LP[2][cb]);
      gl_lds16(Bag + gb, &LP[3][cb]);
      gl_lds16(Bbg + gb, &LP[4][cb]);
      gl_lds16(Bcg + gb, &LP[5][cb]);
    }
    __syncthreads();
    // hoist all 12 B fragments; asm keep-alive pins them in VGPRs (rule #17)
    short8v b1[4], b2[4], b3[4];
#pragma unroll
    for (int j = 0; j < 4; j++) {
      int brow = wn * 64 + j * 16 + ln;
      int boff = brow * 32 + ((g ^ ((brow >> 1) & 3)) * 8);
      b1[j] = *reinterpret_cast<const short8v*>(&LP[3][boff]);
      b2[j] = *reinterpret_cast<const short8v*>(&LP[4][boff]);
      b3[j] = *reinterpret_cast<const short8v*>(&LP[5][boff]);
    }
#pragma unroll
    for (int i = 0; i < 4; i++) {
      asm volatile("" ::"v"(b1[0]), "v"(b1[1]), "v"(b1[2]), "v"(b1[3]), "v"(b2[0]), "v"(b2[1]),
                   "v"(b2[2]), "v"(b2[3]), "v"(b3[0]), "v"(b3[1]), "v"(b3[2]), "v"(b3[3]));
      int arow = wm * 64 + i * 16 + ln;
      int aoff = arow * 32 + ((g ^ ((arow >> 1) & 3)) * 8);
      short8v a1 = *reinterpret_cast<const short8v*>(&LP[0][aoff]);
      short8v a2 = *reinterpret_cast<const short8v*>(&LP[1][aoff]);
      short8v a3 = *reinterpret_cast<const short8v*>(&LP[2][aoff]);
#pragma unroll
      for (int j = 0; j < 4; j++) {
        acc[i][j] = __builtin_amdgcn_mfma_f32_16x16x32_bf16(a1, b1[j], acc[i][j], 0, 0, 0);
        acc[i][j] = __builtin_amdgcn_mfma_f32_16x16x32_bf16(a1, b2[j], acc[i][j], 0, 0, 0);
        acc[i][j] = __builtin_amdgcn_mfma_f32_16x16x32_bf16(a2, b1[j], acc[i][j], 0, 0, 0);
        acc[i][j] = __builtin_amdgcn_mfma_f32_16x16x32_bf16(a1, b3[j], acc[i][j], 0, 0, 0);
        acc[i][j] = __builtin_amdgcn_mfma_f32_16x16x32_bf16(a2, b2[j], acc[i][j], 0, 0, 0);
        acc[i][j] = __builtin_amdgcn_mfma_f32_16x16x32_bf16(a3, b1[j], acc[i][j], 0, 0, 0);
      }
    }
  }
#pragma unroll
  for (int i = 0; i < 4; i++)
#pragma unroll
    for (int j = 0; j < 4; j++)
#pragma unroll
      for (int r = 0; r < 4; r++)
        C[(size_t)(row0 + wm * 64 + i * 16 + g * 4 + r) * N + col0 + wn * 64 + j * 16 + ln] =
            acc[i][j][r];
}

// ===== 6-product GEMM, A pre-split, B split in-kernel (fallback) =====
__global__ __launch_bounds__(256) void gemm6h(const short* __restrict__ Aag,
                                              const short* __restrict__ Abg,
                                              const short* __restrict__ Acg,
                                              const float* __restrict__ B,
                                              float* __restrict__ C, int M, int N, int K) {
  __shared__ short Aa[128 * 40], Ab[128 * 40], Ac[128 * 40];
  __shared__ short Ba[128 * 40], Bb[128 * 40], Bc[128 * 40];
  const int tid = threadIdx.x;
  const int w = tid >> 6, l = tid & 63, g = l >> 4, ln = l & 15;
  const int wm = w >> 1, wn = w & 1;
  const int row0 = blockIdx.y * 128, col0 = blockIdx.x * 128;
  floatx4 acc[4][4] = {};
  for (int k0 = 0; k0 < K; k0 += 32) {
    __syncthreads();
#pragma unroll
    for (int i = 0; i < 2; i++) {
      int id = tid + i * 256;
      int r = id >> 2, c = id & 3;
      size_t ga = (size_t)(row0 + r) * K + k0 + c * 8;
      int o = r * 40 + c * 8;
      *reinterpret_cast<short8v*>(&Aa[o]) = *reinterpret_cast<const short8v*>(&Aag[ga]);
      *reinterpret_cast<short8v*>(&Ab[o]) = *reinterpret_cast<const short8v*>(&Abg[ga]);
      *reinterpret_cast<short8v*>(&Ac[o]) = *reinterpret_cast<const short8v*>(&Acg[ga]);
    }
#pragma unroll
    for (int i = 0; i < 4; i++) {
      int id = tid + i * 256;
      int r = id >> 3, c4 = id & 7;
      float4 bv = *reinterpret_cast<const float4*>(&B[(size_t)(col0 + r) * K + k0 + c4 * 4]);
      float bf[4] = {bv.x, bv.y, bv.z, bv.w};
      short4v b1, b2, b3;
#pragma unroll
      for (int j = 0; j < 4; j++) {
        Split3 t = split3(bf[j]);
        b1[j] = t.a; b2[j] = t.b; b3[j] = t.c;
      }
      int o = r * 40 + c4 * 4;
      *reinterpret_cast<short4v*>(&Ba[o]) = b1;
      *reinterpret_cast<short4v*>(&Bb[o]) = b2;
      *reinterpret_cast<short4v*>(&Bc[o]) = b3;
    }
    __syncthreads();
#pragma unroll
    for (int i = 0; i < 4; i++) {
      int ar = (wm * 64 + i * 16 + ln) * 40 + g * 8;
      short8v a1 = *reinterpret_cast<const short8v*>(&Aa[ar]);
      short8v a2 = *reinterpret_cast<const short8v*>(&Ab[ar]);
      short8v a3 = *reinterpret_cast<const short8v*>(&Ac[ar]);
#pragma unroll
      for (int j = 0; j < 4; j++) {
        int br = (wn * 64 + j * 16 + ln) * 40 + g * 8;
        short8v b1 = *reinterpret_cast<const short8v*>(&Ba[br]);
        short8v b2 = *reinterpret_cast<const short8v*>(&Bb[br]);
        short8v b3 = *reinterpret_cast<const short8v*>(&Bc[br]);
        acc[i][j] = __builtin_amdgcn_mfma_f32_16x16x32_bf16(a1, b1, acc[i][j], 0, 0, 0);
        acc[i][j] = __builtin_amdgcn_mfma_f32_16x16x32_bf16(a1, b2, acc[i][j], 0, 0, 0);
        acc[i][j] = __builtin_amdgcn_mfma_f32_16x16x32_bf16(a2, b1, acc[i][j], 0, 0, 0);
        acc[i][j] = __builtin_amdgcn_mfma_f32_16x16x32_bf16(a1, b3, acc[i][j], 0, 0, 0);
        acc[i][j] = __builtin_amdgcn_mfma_f32_16x16x32_bf16(a2, b2, acc[i][j], 0, 0, 0);
        acc[i][j] = __builtin_amdgcn_mfma_f32_16x16x32_bf16(a3, b1, acc[i][j], 0, 0, 0);
      }
    }
  }
#pragma unroll
  for (int i = 0; i < 4; i++)
#pragma unroll
    for (int j = 0; j < 4; j++)
#pragma unroll
      for (int r = 0; r < 4; r++)
        C[(size_t)(row0 + wm * 64 + i * 16 + g * 4 + r) * N + col0 + wn * 64 + j * 16 + ln] =
            acc[i][j][r];
}

// ===== pure-bf16 GEMM: C = A[M][K] * B[N][K]^T, gl_lds dbuf staging =====
template <int TOUT>
__global__ __launch_bounds__(256, 3) void gemm_bb(const short* __restrict__ A,
                                                  const short* __restrict__ B, void* Cv, int M,
                                                  int N, int K) {
  __shared__ short KS[2][2][128 * 32];  // 32KB dbuf
  const int tid = threadIdx.x;
  const int w = tid >> 6, l = tid & 63, g = l >> 4, ln = l & 15;
  const int wm = w >> 1, wn = w & 1;
  const int row0 = blockIdx.y * 128, col0 = blockIdx.x * 128;
  const int wb = tid & 192;
  floatx4 acc[4][4] = {};
  const int nt = K / 32;
  auto issue = [&](int k0, int buf) {
#pragma unroll
    for (int it = 0; it < 2; it++) {
      int id = it * 256 + tid;
      int r = id >> 2, j = id & 3;
      int cg = j ^ ((r >> 1) & 3);
      size_t ga = (size_t)(row0 + r) * K + k0 + cg * 8;
      size_t gb = (size_t)(col0 + r) * K + k0 + cg * 8;
      int cb = (it * 256 + wb) * 8;
      gl_lds16(A + ga, &KS[buf][0][cb]);
      gl_lds16(B + gb, &KS[buf][1][cb]);
    }
  };
  issue(0, 0);
  __syncthreads();
  for (int t = 0; t < nt; t++) {
    const int cur = t & 1;
    if (t + 1 < nt) issue((t + 1) * 32, cur ^ 1);
    short8v b[4];
#pragma unroll
    for (int j = 0; j < 4; j++) {
      int brow = wn * 64 + j * 16 + ln;
      b[j] = *reinterpret_cast<const short8v*>(
          &KS[cur][1][brow * 32 + ((g ^ ((brow >> 1) & 3)) * 8)]);
    }
#pragma unroll
    for (int i = 0; i < 4; i++) {
      asm volatile("" ::"v"(b[0]), "v"(b[1]), "v"(b[2]), "v"(b[3]));
      int arow = wm * 64 + i * 16 + ln;
      short8v a = *reinterpret_cast<const short8v*>(
          &KS[cur][0][arow * 32 + ((g ^ ((arow >> 1) & 3)) * 8)]);
#pragma unroll
      for (int j = 0; j < 4; j++)
        acc[i][j] = __builtin_amdgcn_mfma_f32_16x16x32_bf16(a, b[j], acc[i][j], 0, 0, 0);
    }
    __syncthreads();
  }
  if (TOUT == 0) {
    float* C = (float*)Cv;
#pragma unroll
    for (int i = 0; i < 4; i++)
#pragma unroll
      for (int j = 0; j < 4; j++)
#pragma unroll
        for (int r = 0; r < 4; r++)
          C[(size_t)(row0 + wm * 64 + i * 16 + g * 4 + r) * N + col0 + wn * 64 + j * 16 + ln] =
              acc[i][j][r];
  } else {
    ushort* Vt = (ushort*)Cv;
#pragma unroll
    for (int i = 0; i < 4; i++)
#pragma unroll
      for (int j = 0; j < 4; j++) {
        short4v o;
#pragma unroll
        for (int r = 0; r < 4; r++) o[r] = (short)f2bf(acc[i][j][r]);
        size_t n = col0 + wn * 64 + j * 16 + ln;
        size_t m0 = row0 + wm * 64 + i * 16 + g * 4;
        *reinterpret_cast<short4v*>(&Vt[n * M + m0]) = o;
      }
  }
}

// ===== RoPE + 3-way split of Q,K =====
__global__ void rope_convert(const float* __restrict__ Q, const float* __restrict__ K,
                             const int* __restrict__ pos, short* __restrict__ Qa,
                             short* __restrict__ Qb, short* __restrict__ Qc,
                             short* __restrict__ Ka, short* __restrict__ Kb,
                             short* __restrict__ Kc) {
  int idx = blockIdx.x * blockDim.x + threadIdx.x;
  if (idx >= S_LEN * 64) return;
  int d = idx & 63;
  int r = idx >> 6;
  float p = (float)pos[r];
  float invf = (float)pow(10000.0, -(double)(2 * d) / 128.0);
  float ang = p * invf;
  float c = cosf(ang), s = sinf(ang);
  for (int h = 0; h < NH; h++) {
    size_t base = (size_t)r * DMODEL + h * HDIM + d;
    float q1 = Q[base], q2 = Q[base + 64];
    float k1 = K[base], k2 = K[base + 64];
    float qa = q1 * c - q2 * s, qb = q2 * c + q1 * s;
    float ka = k1 * c - k2 * s, kb = k2 * c + k1 * s;
    Split3 t;
    t = split3(qa); Qa[base] = t.a; Qb[base] = t.b; Qc[base] = t.c;
    t = split3(qb); Qa[base + 64] = t.a; Qb[base + 64] = t.b; Qc[base + 64] = t.c;
    t = split3(ka); Ka[base] = t.a; Kb[base] = t.b; Kc[base] = t.c;
    t = split3(kb); Ka[base + 64] = t.a; Kb[base + 64] = t.b; Kc[base + 64] = t.c;
  }
}

// ===== fused flash attention: QB=64, 4 waves, bound-softmax, dbuf gl_lds =====
#define KVB 32
#define KSPL (KVB * 128)

__device__ __forceinline__ floatx4 qk6_tile(const short* KaS, const short* KbS,
                                            const short* KcS, const short8v q1[4],
                                            const short8v q2[4], const short8v q3[4],
                                            int krow, int g) {
  floatx4 cA = {}, cB = {}, cC = {}, cD = {}, cE = {}, cF = {};
#pragma unroll
  for (int dc = 0; dc < 4; dc++) {
    int didx = krow * 128 + ((dc * 32 + g * 8) ^ ((krow & 7) << 3));
    short8v k1 = *reinterpret_cast<const short8v*>(&KaS[didx]);
    short8v k2 = *reinterpret_cast<const short8v*>(&KbS[didx]);
    short8v k3 = *reinterpret_cast<const short8v*>(&KcS[didx]);
    cA = __builtin_amdgcn_mfma_f32_16x16x32_bf16(q1[dc], k1, cA, 0, 0, 0);
    cB = __builtin_amdgcn_mfma_f32_16x16x32_bf16(q1[dc], k2, cB, 0, 0, 0);
    cC = __builtin_amdgcn_mfma_f32_16x16x32_bf16(q2[dc], k1, cC, 0, 0, 0);
    cD = __builtin_amdgcn_mfma_f32_16x16x32_bf16(q1[dc], k3, cD, 0, 0, 0);
    cE = __builtin_amdgcn_mfma_f32_16x16x32_bf16(q2[dc], k2, cE, 0, 0, 0);
    cF = __builtin_amdgcn_mfma_f32_16x16x32_bf16(q3[dc], k1, cF, 0, 0, 0);
  }
  return ((cA + cB) + (cC + cD)) + (cE + cF);
}

__device__ __forceinline__ void issue_tile(const short* __restrict__ Ka,
                                           const short* __restrict__ Kb,
                                           const short* __restrict__ Kc, int k0, int h,
                                           short* bufA, short* bufB, short* bufC, int tid) {
  const int wb = tid & 192;
#pragma unroll
  for (int it = 0; it < 2; it++) {
    int j = it * 256 + tid;
    int r = j >> 4, cl = j & 15;
    int cg = cl ^ (r & 7);
    size_t goff = (size_t)(k0 + r) * DMODEL + h * HDIM + cg * 8;
    int cb = (it * 256 + wb) * 8;
    gl_lds16(Ka + goff, bufA + cb);
    gl_lds16(Kb + goff, bufB + cb);
    gl_lds16(Kc + goff, bufC + cb);
  }
}

__global__ __launch_bounds__(256, 3) void attn_fused(
    const short* __restrict__ Qa, const short* __restrict__ Qb, const short* __restrict__ Qc,
    const short* __restrict__ Ka, const short* __restrict__ Kb, const short* __restrict__ Kc,
    const ushort* __restrict__ Vt, const float* __restrict__ qn,
    const float* __restrict__ mk2p, ushort* __restrict__ AObf, float* __restrict__ sp4) {
  __shared__ short KS[2][3][KSPL];  // 48KB
  __shared__ short Ps[4 * 512];     // 4KB
  const int bid = blockIdx.x;
  const int qb = 31 - (bid >> 5);  // LPT
  const int h = bid & 31;
  const int tid = threadIdx.x;
  const int w = tid >> 6, g = (tid >> 4) & 3, ln = tid & 15;
  const int q0 = qb * 64;
  const int qrow = q0 + w * 16 + ln;
  short8v q1[4], q2[4], q3[4];
#pragma unroll
  for (int dc = 0; dc < 4; dc++) {
    size_t off = (size_t)qrow * DMODEL + h * HDIM + dc * 32 + g * 8;
    q1[dc] = *reinterpret_cast<const short8v*>(&Qa[off]);
    q2[dc] = *reinterpret_cast<const short8v*>(&Qb[off]);
    q3[dc] = *reinterpret_cast<const short8v*>(&Qc[off]);
  }
  float mkv = 0.f;
#pragma unroll
  for (int j = 0; j < 16; j++) mkv = fmaxf(mkv, mk2p[h * 16 + j]);
  const float mk = sqrtf(mkv);
  float B_r[4], l_r[4];
#pragma unroll
  for (int r = 0; r < 4; r++) {
    B_r[r] = qn[h * S_LEN + q0 + w * 16 + g * 4 + r] * mk * ATTN_SCALE;
    l_r[r] = 0.f;
  }
  const int nkt = 2 * qb + 2;

  // ---- pass 1 ----
  issue_tile(Ka, Kb, Kc, 0, h, KS[0][0], KS[0][1], KS[0][2], tid);
  __syncthreads();
  for (int t = 0; t < nkt; t++) {
    const int k0 = t * KVB;
    const int cur = t & 1;
    if (t + 1 < nkt)
      issue_tile(Ka, Kb, Kc, k0 + KVB, h, KS[cur ^ 1][0], KS[cur ^ 1][1], KS[cur ^ 1][2], tid);
#pragma unroll
    for (int ct = 0; ct < 2; ct++) {
      floatx4 sacc = qk6_tile(KS[cur][0], KS[cur][1], KS[cur][2], q1, q2, q3, ct * 16 + ln, g);
#pragma unroll
      for (int r = 0; r < 4; r++) {
        float s = sacc[r] * ATTN_SCALE;
        int key = k0 + ct * 16 + ln;
        int qq = q0 + w * 16 + g * 4 + r;
        l_r[r] += (key <= qq) ? __expf(s - B_r[r]) : 0.f;
      }
    }
    __syncthreads();
  }
  float inv_l[4];
#pragma unroll
  for (int r = 0; r < 4; r++) {
    float l = l_r[r];
    l += __shfl_xor(l, 1);
    l += __shfl_xor(l, 2);
    l += __shfl_xor(l, 4);
    l += __shfl_xor(l, 8);
    inv_l[r] = 1.0f / l;
  }

  // ---- pass 2 ----
  floatx4 o[8] = {};
  issue_tile(Ka, Kb, Kc, 0, h, KS[0][0], KS[0][1], KS[0][2], tid);
  __syncthreads();
  for (int t = 0; t < nkt; t++) {
    const int k0 = t * KVB;
    const int cur = t & 1;
    if (t + 1 < nkt)
      issue_tile(Ka, Kb, Kc, k0 + KVB, h, KS[cur ^ 1][0], KS[cur ^ 1][1], KS[cur ^ 1][2], tid);
    float pv[2][4];
#pragma unroll
    for (int ct = 0; ct < 2; ct++) {
      floatx4 sacc = qk6_tile(KS[cur][0], KS[cur][1], KS[cur][2], q1, q2, q3, ct * 16 + ln, g);
#pragma unroll
      for (int r = 0; r < 4; r++) {
        float s = sacc[r] * ATTN_SCALE;
        int key = k0 + ct * 16 + ln;
        int qq = q0 + w * 16 + g * 4 + r;
        float e = (key <= qq) ? __expf(s - B_r[r]) : 0.f;
        pv[ct][r] = e * inv_l[r];
      }
    }
#pragma unroll
    for (int ct = 0; ct < 2; ct++) {
      float c2 = pv[ct][0] + pv[ct][1] + pv[ct][2] + pv[ct][3];
      c2 += __shfl_xor(c2, 16);
      c2 += __shfl_xor(c2, 32);
      if (g == 0) sp4[((size_t)(qb * 4 + w) * NH + h) * S_LEN + k0 + ct * 16 + ln] = c2;
    }
#pragma unroll
    for (int ct = 0; ct < 2; ct++)
#pragma unroll
      for (int r = 0; r < 4; r++) {
        int prow = g * 4 + r, pcol = ct * 16 + ln;
        int col = ((((pcol >> 3) ^ (prow >> 2)) & 3) << 3) | (pcol & 7);
        Ps[w * 512 + prow * 32 + col] = (short)f2bf(pv[ct][r]);
      }
    short8v pa = *reinterpret_cast<const short8v*>(
        &Ps[w * 512 + ln * 32 + (((g ^ (ln >> 2)) & 3) << 3)]);
#pragma unroll
    for (int ctd = 0; ctd < 8; ctd++) {
      size_t voff = ((size_t)h * HDIM + ctd * 16 + ln) * S_LEN + k0 + g * 8;
      short8v vb = *reinterpret_cast<const short8v*>(&Vt[voff]);
      o[ctd] = __builtin_amdgcn_mfma_f32_16x16x32_bf16(pa, vb, o[ctd], 0, 0, 0);
    }
    __syncthreads();
  }
#pragma unroll
  for (int ctd = 0; ctd < 8; ctd++)
#pragma unroll
    for (int r = 0; r < 4; r++)
      AObf[(size_t)(q0 + w * 16 + g * 4 + r) * DMODEL + h * HDIM + ctd * 16 + ln] =
          f2bf(o[ctd][r]);
}

// ---------------- reduce column-sum partials (128 per (h,k)) ----------------
__global__ void reduce_scores(const float* __restrict__ sp4, float* __restrict__ scores) {
  int idx = blockIdx.x * blockDim.x + threadIdx.x;
  if (idx >= NH * S_LEN) return;
  int h = idx >> 11, k = idx & 2047;
  float s = 0.f;
  for (int j = 0; j < 128; j++) s += sp4[((size_t)j * NH + h) * S_LEN + k];
  scores[idx] = s;
}

// ---------------- per-head exact top-256 + mask + previous_scores ----------------
__global__ __launch_bounds__(256) void topk_mask_kernel(const float* __restrict__ scores,
                                                        float* __restrict__ out_mask,
                                                        float* __restrict__ prev_scores) {
  const int h = blockIdx.x;
  __shared__ unsigned sb[S_LEN - RECENT];
  __shared__ int cnt_sh;
  const int NSEL = S_LEN - RECENT;
  const int tid = threadIdx.x;
  const float* sc = scores + (size_t)h * S_LEN;
  for (int i = tid; i < NSEL; i += 256) sb[i] = __float_as_uint(sc[i]);
  __syncthreads();
  unsigned prefix = 0u;
  for (int b = 31; b >= 0; b--) {
    unsigned cand = prefix | (1u << b);
    if (tid == 0) cnt_sh = 0;
    __syncthreads();
    int c = 0;
    for (int i = tid; i < NSEL; i += 256) c += (sb[i] >= cand) ? 1 : 0;
    atomicAdd(&cnt_sh, c);
    __syncthreads();
    if (cnt_sh >= HEAVY) prefix = cand;
    __syncthreads();
  }
  if (tid == 0) cnt_sh = 0;
  __syncthreads();
  int c = 0;
  for (int i = tid; i < NSEL; i += 256) c += (sb[i] > prefix) ? 1 : 0;
  atomicAdd(&cnt_sh, c);
  __syncthreads();
  const int c1 = cnt_sh;
  float* mrow = out_mask + (size_t)h * (S_LEN + 1);
  float* prow = prev_scores + (size_t)h * S_LEN;
  for (int j = NSEL + tid; j < S_LEN + 1; j += 256) mrow[j] = 1.0f;
  for (int k = NSEL + tid; k < S_LEN; k += 256) prow[k] = sc[k];
  for (int i = tid; i < NSEL; i += 256) {
    bool sel = sb[i] > prefix;
    mrow[i] = sel ? 1.f : 0.f;
    prow[i] = sel ? sc[i] : 0.f;
  }
  __syncthreads();
  if (tid == 0) {
    int need = HEAVY - c1;
    for (int i = 0; i < NSEL && need > 0; i++) {
      if (sb[i] == prefix) { mrow[i] = 1.f; prow[i] = sc[i]; need--; }
    }
  }
}

extern "C" void kernel_launch(void* const* d_in, const int* in_sizes, int n_in,
                              void* d_out, int out_size, void* d_ws, size_t ws_size,
                              hipStream_t stream) {
  const float* hidden = (const float*)d_in[0];
  const int* pos = (const int*)d_in[2];
  const float* Wq = (const float*)d_in[3];
  const float* Wk = (const float*)d_in[4];
  const float* Wv = (const float*)d_in[5];
  const float* Wo = (const float*)d_in[6];

  float* out0 = (float*)d_out;
  float* out_mask = out0 + (size_t)S_LEN * DMODEL;
  float* prev_scores = out_mask + (size_t)NH * (S_LEN + 1);

  char* ws = (char*)d_ws;
  float* Qf = (float*)(ws + 0 * MB);
  float* Kf = (float*)(ws + 32 * MB);
  ushort* Vt = (ushort*)(ws + 64 * MB);
  short* Ha = (short*)(ws + 80 * MB);
  short* Hb = (short*)(ws + 96 * MB);
  short* Hc = (short*)(ws + 112 * MB);
  short* Qa = (short*)(ws + 80 * MB);
  short* Qb = (short*)(ws + 96 * MB);
  short* Qc = (short*)(ws + 112 * MB);
  short* Ka = (short*)(ws + 128 * MB);
  short* Kb = (short*)(ws + 144 * MB);
  short* Kc = (short*)(ws + 160 * MB);
  ushort* AObf = (ushort*)(ws + 0 * MB);
  float* sp4 = Kf;
  float* scores = (float*)(ws + 64 * MB);
  ushort* Wobf = (ushort*)(ws + 96 * MB);

  float* qn = out0;
  float* mk2p = out0 + NH * S_LEN;

  dim3 gg(DMODEL / 128, S_LEN / 128);
  split_mat<<<2048, 256, 0, stream>>>(hidden, Ha, Hb, Hc, S_LEN * DMODEL / 4);

  ushort* Wvbf;
  if (ws_size >= 224 * MB) {
    short* Wsa = (short*)(ws + 128 * MB);
    short* Wsb = (short*)(ws + 160 * MB);
    short* Wsc = (short*)(ws + 192 * MB);
    split_mat<<<2048, 256, 0, stream>>>(Wq, Wsa, Wsb, Wsc, DMODEL * DMODEL / 4);
    gemm6p<<<gg, 256, 0, stream>>>(Ha, Hb, Hc, Wsa, Wsb, Wsc, Qf, S_LEN, DMODEL, DMODEL);
    split_mat<<<2048, 256, 0, stream>>>(Wk, Wsa, Wsb, Wsc, DMODEL * DMODEL / 4);
    gemm6p<<<gg, 256, 0, stream>>>(Ha, Hb, Hc, Wsa, Wsb, Wsc, Kf, S_LEN, DMODEL, DMODEL);
    Wvbf = (ushort*)(ws + 192 * MB);
  } else {
    gemm6h<<<gg, 256, 0, stream>>>(Ha, Hb, Hc, Wq, Qf, S_LEN, DMODEL, DMODEL);
    gemm6h<<<gg, 256, 0, stream>>>(Ha, Hb, Hc, Wk, Kf, S_LEN, DMODEL, DMODEL);
    Wvbf = (ushort*)(ws + 128 * MB);
  }
  to_bf16<<<2048, 256, 0, stream>>>(Wv, Wvbf, DMODEL * DMODEL / 4);
  gemm_bb<1><<<gg, 256, 0, stream>>>(Ha, (const short*)Wvbf, Vt, S_LEN, DMODEL, DMODEL);

  norms_kernel<<<512, 256, 0, stream>>>(Qf, Kf, qn, mk2p);

  int rope_total = S_LEN * 64;
  rope_convert<<<(rope_total + 255) / 256, 256, 0, stream>>>(Qf, Kf, pos, Qa, Qb, Qc, Ka, Kb, Kc);

  hipError_t _e = hipMemsetAsync(sp4, 0, (size_t)128 * NH * S_LEN * sizeof(float), stream);
  (void)_e;
  attn_fused<<<1024, 256, 0, stream>>>(Qa, Qb, Qc, Ka, Kb, Kc, Vt, qn, mk2p, AObf, sp4);

  to_bf16<<<2048, 256, 0, stream>>>(Wo, Wobf, DMODEL * DMODEL / 4);
  reduce_scores<<<(NH * S_LEN + 255) / 256, 256, 0, stream>>>(sp4, scores);
  topk_mask_kernel<<<NH, 256, 0, stream>>>(scores, out_mask, prev_scores);

  gemm_bb<0><<<gg, 256, 0, stream>>>((const short*)AObf, (const short*)Wobf, out0, S_LEN, DMODEL,
                                     DMODEL);
}